// Round 14
// baseline (1047.497 us; speedup 1.0000x reference)
//
#include <hip/hip_runtime.h>
#include <hip/hip_bf16.h>
#include <stdint.h>

// ---------------------------------------------------------------------------
// TernaryExpert via INT8 MFMA (R14 = R13 with occupancy 2 blocks/CU):
// double-buffered 64KB LDS (was triple 96KB) + __launch_bounds__(512,4)
// -> 16 waves/CU. Shallow stage-next-tile pipeline (vmcnt(0)+1 barrier per
// K-tile); the inter-block overlap (m97/m114 regime) hides the drain.
// Numerics identical to R13: xq = rn(24*x_norm), hq = rn(gelu(acc/24)),
// out = acc * rs[row], rs from hq itself. absmax expected exactly 5.0.
// GEMM: 256x256, BK=64, 8 waves (2Mx4N, 128x64/wave), mfma_i32_16x16x64_i8,
// swizzle chunk ^= (row>>1)&3 both sides (2-way = free, 0 conflicts R13).
// ---------------------------------------------------------------------------

#define M_ROWS   16384
#define D_MODEL  1024
#define D_FF     4096
#define NW       (D_FF * D_MODEL)

typedef __attribute__((ext_vector_type(4))) int   i32x4;
typedef __attribute__((ext_vector_type(4))) float f32x4;

__device__ __forceinline__ void gload_lds16(const void* g, void* l) {
    __builtin_amdgcn_global_load_lds(
        (const __attribute__((address_space(1))) void*)g,
        (__attribute__((address_space(3))) void*)l, 16, 0, 0);
}

#define BAR()     __builtin_amdgcn_s_barrier()
#define VMCNT(n)  asm volatile("s_waitcnt vmcnt(" #n ")" ::: "memory")

__device__ __forceinline__ float gelu_fast(float v) {
    float w = v * v;
    float z = v * __builtin_fmaf(w, 0.07135481627f, 1.5957691216f);
    float e = __expf(-z);
    return v / (1.0f + e);
}
__device__ __forceinline__ int q8(float v) {
    int q = __float2int_rn(v);
    return (q > 127) ? 127 : ((q < -127) ? -127 : q);
}

// ---------------------------------------------------------------------------
// aux kernels (identical to R13)
// ---------------------------------------------------------------------------
__global__ __launch_bounds__(256) void absmean_reduce(const float* __restrict__ w,
                                                      double* __restrict__ asum) {
    const int n4 = NW / 4;
    float s = 0.f;
    const float4* w4 = (const float4*)w;
    for (int i = blockIdx.x * blockDim.x + threadIdx.x; i < n4;
         i += gridDim.x * blockDim.x) {
        float4 v = w4[i];
        s += fabsf(v.x) + fabsf(v.y) + fabsf(v.z) + fabsf(v.w);
    }
    #pragma unroll
    for (int off = 32; off > 0; off >>= 1) s += __shfl_down(s, off);
    __shared__ float sm[4];
    int lane = threadIdx.x & 63, wid = threadIdx.x >> 6;
    if (lane == 0) sm[wid] = s;
    __syncthreads();
    if (threadIdx.x == 0) {
        float t = sm[0] + sm[1] + sm[2] + sm[3];
        atomicAdd(asum, (double)t);
    }
}

__global__ __launch_bounds__(256) void quant_w8(const float* __restrict__ w,
                                                const double* __restrict__ asum,
                                                char* __restrict__ wq) {
    float thr = (float)(0.5 * (*asum) * (1.0 / (double)NW));
    int i = blockIdx.x * blockDim.x + threadIdx.x;
    float4 v = ((const float4*)w)[i];
    int b0 = (fabsf(v.x) > thr) ? (v.x > 0.f ? 1 : -1) : 0;
    int b1 = (fabsf(v.y) > thr) ? (v.y > 0.f ? 1 : -1) : 0;
    int b2 = (fabsf(v.z) > thr) ? (v.z > 0.f ? 1 : -1) : 0;
    int b3 = (fabsf(v.w) > thr) ? (v.w > 0.f ? 1 : -1) : 0;
    ((int*)wq)[i] = (b0 & 0xff) | ((b1 & 0xff) << 8) |
                    ((b2 & 0xff) << 16) | ((b3 & 0xff) << 24);
}

__global__ __launch_bounds__(256) void rmsnorm_xq(const float* __restrict__ x,
                                                  char* __restrict__ xq) {
    const int row = blockIdx.x;
    const float4* xr = (const float4*)(x + (size_t)row * D_MODEL);
    float4 v = xr[threadIdx.x];
    float ss = v.x * v.x + v.y * v.y + v.z * v.z + v.w * v.w;
    #pragma unroll
    for (int off = 32; off > 0; off >>= 1) ss += __shfl_down(ss, off);
    __shared__ float sm[4];
    int lane = threadIdx.x & 63, wid = threadIdx.x >> 6;
    if (lane == 0) sm[wid] = ss;
    __syncthreads();
    float tot = sm[0] + sm[1] + sm[2] + sm[3];
    float s = 24.0f / (sqrtf(tot) * (1.0f / 32.0f) + 1e-8f);
    int b0 = q8(v.x * s), b1 = q8(v.y * s), b2 = q8(v.z * s), b3 = q8(v.w * s);
    ((int*)(xq + (size_t)row * D_MODEL))[threadIdx.x] =
        (b0 & 0xff) | ((b1 & 0xff) << 8) | ((b2 & 0xff) << 16) | ((b3 & 0xff) << 24);
}

__global__ __launch_bounds__(256) void rowscale_hq(const char* __restrict__ hq,
                                                   float* __restrict__ rs) {
    const int row = blockIdx.x;
    const int4* hr = (const int4*)(hq + (size_t)row * D_FF);
    int4 d = hr[threadIdx.x];
    float ss = 0.f;
    #pragma unroll
    for (int w = 0; w < 4; ++w) {
        int dw = (w == 0) ? d.x : (w == 1) ? d.y : (w == 2) ? d.z : d.w;
        #pragma unroll
        for (int b = 0; b < 4; ++b) {
            int q = (int)(char)((dw >> (8 * b)) & 0xff);
            ss += (float)(q * q);
        }
    }
    #pragma unroll
    for (int off = 32; off > 0; off >>= 1) ss += __shfl_down(ss, off);
    __shared__ float sm[4];
    int lane = threadIdx.x & 63, wid = threadIdx.x >> 6;
    if (lane == 0) sm[wid] = ss;
    __syncthreads();
    if (threadIdx.x == 0) {
        float tot = sm[0] + sm[1] + sm[2] + sm[3];
        rs[row] = 1.0f / (sqrtf(tot) * (1.0f / 64.0f) + 1e-8f);
    }
}

// ---------------------------------------------------------------------------
// i8 GEMM: C[m][n] = sum_k A[m,k]*B[n,k], A/B i8 K-contig.
// LDS buffer (32KB): A 256x64B @0, B 256x64B @16384. 2 buffers (64KB)
// -> 2 blocks/CU. Stage t+1 into buf[t&1^1]; vmcnt(0)+barrier per tile.
// WAR: buf[nxt]'s tile-(t-1) reads were consumed (per-wave lgkm before MFMA)
// before the end-of-(t-1) barrier; staging into it is issued after.
// ---------------------------------------------------------------------------
template <int EPI, int KDIM, int NBLKN>
__global__ __launch_bounds__(512, 4) void gemm_i8(const char* __restrict__ A,
                                                  const char* __restrict__ B,
                                                  char* __restrict__ Cq,
                                                  float* __restrict__ Cf,
                                                  const float* __restrict__ rowscale,
                                                  int nwg) {
    constexpr int BUFB = 32768;
    constexpr int NT = KDIM / 64;
    __shared__ char smem[2 * BUFB];

    const int tid = threadIdx.x;
    const int bid = blockIdx.x;
    const int swz = (bid & 7) * (nwg >> 3) + (bid >> 3);
    const uint m0 = (uint)(swz / NBLKN) * 256u;
    const uint n0 = (uint)(swz % NBLKN) * 256u;

    const int lane = tid & 63;
    const int wid  = tid >> 6;
    const int wm   = wid >> 2;                  // 0..1 -> 128-row slice
    const int wn   = wid & 3;                   // 0..3 -> 64-col slice
    const int lr   = lane & 15;
    const int lk   = lane >> 4;                 // 16B k-chunk 0..3

    // staging source (inverse swizzle), per inst in {0,1}
    uint aOff[2], bOff[2];
    #pragma unroll
    for (int inst = 0; inst < 2; ++inst) {
        uint s = (uint)tid + (uint)inst * 512u;
        uint row = s >> 2, ch = s & 3u;
        uint src = ((ch ^ ((row >> 1) & 3u)) << 4);
        aOff[inst] = (m0 + row) * (uint)KDIM + src;
        bOff[inst] = (n0 + row) * (uint)KDIM + src;
    }
    const uint dstOff = (uint)tid * 16u;

    // fragment read offsets (bytes)
    uint offA[8], offB[4];
    #pragma unroll
    for (int i = 0; i < 8; ++i) {
        uint row = (uint)(wm * 128 + i * 16 + lr);
        offA[i] = row * 64u + (((uint)lk ^ ((row >> 1) & 3u)) << 4);
    }
    #pragma unroll
    for (int i = 0; i < 4; ++i) {
        uint row = (uint)(wn * 64 + i * 16 + lr);
        offB[i] = 16384u + row * 64u + (((uint)lk ^ ((row >> 1) & 3u)) << 4);
    }

    i32x4 acc[8][4];
    #pragma unroll
    for (int mi = 0; mi < 8; ++mi)
        #pragma unroll
        for (int ni = 0; ni < 4; ++ni)
            acc[mi][ni] = (i32x4){0, 0, 0, 0};

    // prologue: stage tile 0 into buf 0
    {
        char* sb = smem;
        gload_lds16(A + aOff[0], sb +     0 + dstOff);
        gload_lds16(A + aOff[1], sb +  8192 + dstOff);
        gload_lds16(B + bOff[0], sb + 16384 + dstOff);
        gload_lds16(B + bOff[1], sb + 24576 + dstOff);
    }
    VMCNT(0);
    BAR();

    #pragma unroll 1
    for (int t = 0; t < NT; ++t) {
        const char* cb = smem + (t & 1) * BUFB;
        char* sb = smem + ((t + 1) & 1) * BUFB;
        const uint kc = (uint)(t + 1) * 64u;
        const bool doS = (t + 1 < NT);
        i32x4 av[4], bv[4];

        // ---- P1: A-h0 + all B reads; stage A(t+1); 16 MFMA ----
        #pragma unroll
        for (int i = 0; i < 4; ++i) av[i] = *(const i32x4*)(cb + offA[i]);
        #pragma unroll
        for (int i = 0; i < 4; ++i) bv[i] = *(const i32x4*)(cb + offB[i]);
        if (doS) {
            gload_lds16(A + aOff[0] + kc, sb +    0 + dstOff);
            gload_lds16(A + aOff[1] + kc, sb + 8192 + dstOff);
        }
        __builtin_amdgcn_s_setprio(1);
        #pragma unroll
        for (int mi = 0; mi < 4; ++mi)
            #pragma unroll
            for (int ni = 0; ni < 4; ++ni)
                acc[mi][ni] = __builtin_amdgcn_mfma_i32_16x16x64_i8(
                    av[mi], bv[ni], acc[mi][ni], 0, 0, 0);
        __builtin_amdgcn_s_setprio(0);

        // ---- P2: A-h1 reads (B reg-reused); stage B(t+1); 16 MFMA ----
        #pragma unroll
        for (int i = 0; i < 4; ++i) av[i] = *(const i32x4*)(cb + offA[4 + i]);
        if (doS) {
            gload_lds16(B + bOff[0] + kc, sb + 16384 + dstOff);
            gload_lds16(B + bOff[1] + kc, sb + 24576 + dstOff);
        }
        __builtin_amdgcn_s_setprio(1);
        #pragma unroll
        for (int mi = 0; mi < 4; ++mi)
            #pragma unroll
            for (int ni = 0; ni < 4; ++ni)
                acc[4 + mi][ni] = __builtin_amdgcn_mfma_i32_16x16x64_i8(
                    av[mi], bv[ni], acc[4 + mi][ni], 0, 0, 0);
        __builtin_amdgcn_s_setprio(0);

        if (doS) { VMCNT(0); }     // tile t+1 fully landed
        BAR();
    }

    // epilogue: C/D frag mapping col = lane&15, row = (lane>>4)*4 + reg
    constexpr uint N = (uint)NBLKN * 256u;
    #pragma unroll
    for (int mi = 0; mi < 8; ++mi) {
        #pragma unroll
        for (int j = 0; j < 4; ++j) {
            const uint gr = m0 + (uint)(wm * 128 + mi * 16 + lk * 4 + j);
            float s = 0.f;
            if (EPI == 1) s = rowscale[gr];
            #pragma unroll
            for (int ni = 0; ni < 4; ++ni) {
                const uint gc = n0 + (uint)(wn * 64 + ni * 16 + lr);
                if (EPI == 0) {
                    float g = gelu_fast((float)acc[mi][ni][j] * (1.0f / 24.0f));
                    Cq[gr * N + gc] = (char)q8(g);
                } else {
                    Cf[gr * N + gc] = (float)acc[mi][ni][j] * s;
                }
            }
        }
    }
}

// ---------------------------------------------------------------------------
extern "C" void kernel_launch(void* const* d_in, const int* in_sizes, int n_in,
                              void* d_out, int out_size, void* d_ws, size_t ws_size,
                              hipStream_t stream) {
    const float* x    = (const float*)d_in[0];
    const float* w_up = (const float*)d_in[1];
    const float* w_dn = (const float*)d_in[2];
    float* out = (float*)d_out;

    uint8_t* ws = (uint8_t*)d_ws;
    char* hq  = (char*)(ws);                                   // 64 MB
    char* xq  = (char*)(ws + 67108864);                        // 16 MB
    char* wqu = (char*)(ws + 67108864 + 16777216);             // 4 MB
    char* wqd = (char*)(ws + 67108864 + 16777216 + 4194304);   // 4 MB
    float*  rs   = (float*)(ws + 67108864 + 16777216 + 2 * 4194304);
    double* alph = (double*)(ws + 67108864 + 16777216 + 2 * 4194304 + 65536);

    hipMemsetAsync(alph, 0, 16, stream);

    absmean_reduce<<<256, 256, 0, stream>>>(w_up, alph + 0);
    absmean_reduce<<<256, 256, 0, stream>>>(w_dn, alph + 1);
    quant_w8<<<NW / 1024, 256, 0, stream>>>(w_up, alph + 0, wqu);
    quant_w8<<<NW / 1024, 256, 0, stream>>>(w_dn, alph + 1, wqd);
    rmsnorm_xq<<<M_ROWS, 256, 0, stream>>>(x, xq);

    // L1: hq = q8(gelu((xq @ wqu^T)/24))  [16384 x 4096], K=1024
    gemm_i8<0, D_MODEL, 16><<<1024, 512, 0, stream>>>(
        xq, wqu, hq, nullptr, nullptr, 1024);

    rowscale_hq<<<M_ROWS, 256, 0, stream>>>(hq, rs);

    // L2: out = (hq @ wqd^T) * rs[m]  [16384 x 1024], K=4096
    gemm_i8<1, D_FF, 4><<<256, 512, 0, stream>>>(
        hq, wqd, nullptr, out, rs, 256);
}

// Round 15
// 222.306 us; speedup vs baseline: 4.7120x; 4.7120x over previous
//
#include <hip/hip_runtime.h>
#include <hip/hip_bf16.h>
#include <stdint.h>

// ---------------------------------------------------------------------------
// TernaryExpert via INT8 MFMA (R15 = R13 + B-direct-to-registers):
// R14's occupancy attempt spilled acc (VGPR cap < 128 AGPR) -> reverted.
// Model: R13's wall tracks ~128cy per global_load_lds wave-instruction per
// block. Cut them: B (tiny, L2-hot, redundant) is PRE-PACKED in MFMA
// fragment order (R9-verified technique) and loaded global->VGPR directly
// (asm global_load_dwordx4, 1KB/wave, ping-pong reg sets, 2-tile unroll).
// A stays gload_lds triple-buffered (3 x 16KB, swizzled, R13-identical).
// gload_lds insts/tile: 32 -> 16; staged LDS bytes 32 -> 16KB; ds_read 12->8.
// Waits: end-of-tile vmcnt(2) leaves only A(t+2) in flight (motion-robust);
// B reg deps are compiler-tracked dataflow. Numerics identical to R13
// (absmax 5.0): xq = rn(24*x_norm), hq = rn(gelu(acc/24)), out = acc*rs.
// ---------------------------------------------------------------------------

#define M_ROWS   16384
#define D_MODEL  1024
#define D_FF     4096
#define NW       (D_FF * D_MODEL)

typedef __attribute__((ext_vector_type(4))) int   i32x4;
typedef __attribute__((ext_vector_type(4))) float f32x4;

__device__ __forceinline__ void gload_lds16(const void* g, void* l) {
    __builtin_amdgcn_global_load_lds(
        (const __attribute__((address_space(1))) void*)g,
        (__attribute__((address_space(3))) void*)l, 16, 0, 0);
}

#define BAR()     __builtin_amdgcn_s_barrier()
#define VMCNT(n)  asm volatile("s_waitcnt vmcnt(" #n ")" ::: "memory")

// B fragment load: 64 lanes x 16B contiguous (coalesced 1KB), to regs.
#define LOADB(dst, ptr) \
    asm volatile("global_load_dwordx4 %0, %1, off" : "=v"(dst) : "v"(ptr))

__device__ __forceinline__ float gelu_fast(float v) {
    float w = v * v;
    float z = v * __builtin_fmaf(w, 0.07135481627f, 1.5957691216f);
    float e = __expf(-z);
    return v / (1.0f + e);
}
__device__ __forceinline__ int q8(float v) {
    int q = __float2int_rn(v);
    return (q > 127) ? 127 : ((q < -127) ? -127 : q);
}

// ---------------------------------------------------------------------------
// aux kernels
// ---------------------------------------------------------------------------
__global__ __launch_bounds__(256) void absmean_reduce(const float* __restrict__ w,
                                                      double* __restrict__ asum) {
    const int n4 = NW / 4;
    float s = 0.f;
    const float4* w4 = (const float4*)w;
    for (int i = blockIdx.x * blockDim.x + threadIdx.x; i < n4;
         i += gridDim.x * blockDim.x) {
        float4 v = w4[i];
        s += fabsf(v.x) + fabsf(v.y) + fabsf(v.z) + fabsf(v.w);
    }
    #pragma unroll
    for (int off = 32; off > 0; off >>= 1) s += __shfl_down(s, off);
    __shared__ float sm[4];
    int lane = threadIdx.x & 63, wid = threadIdx.x >> 6;
    if (lane == 0) sm[wid] = s;
    __syncthreads();
    if (threadIdx.x == 0) {
        float t = sm[0] + sm[1] + sm[2] + sm[3];
        atomicAdd(asum, (double)t);
    }
}

// Ternarize -> i8 packed in MFMA-fragment order (R9-verified mapping, i8):
// slot g -> lane = g&63, ks = (g>>6)%KS, nf = (g>>6)/KS;
// holds B[nf*16 + (lane&15), ks*64 + (lane>>4)*16 .. +16]  (16 i8 = 16B).
template <int K>
__global__ __launch_bounds__(256) void quant_pack_i8(const float* __restrict__ w,
                                                     const double* __restrict__ asum,
                                                     char* __restrict__ wq) {
    constexpr int KS = K / 64;
    float thr = (float)(0.5 * (*asum) * (1.0 / (double)NW));
    int g = blockIdx.x * blockDim.x + threadIdx.x;
    int lane = g & 63;
    int rest = g >> 6;
    int ks = rest % KS, nf = rest / KS;
    int row = nf * 16 + (lane & 15);
    int k0  = ks * 64 + (lane >> 4) * 16;
    const float* src = w + (size_t)row * K + k0;
    int out[4];
    #pragma unroll
    for (int q = 0; q < 4; ++q) {
        float4 v = ((const float4*)src)[q];
        int b0 = (fabsf(v.x) > thr) ? (v.x > 0.f ? 1 : -1) : 0;
        int b1 = (fabsf(v.y) > thr) ? (v.y > 0.f ? 1 : -1) : 0;
        int b2 = (fabsf(v.z) > thr) ? (v.z > 0.f ? 1 : -1) : 0;
        int b3 = (fabsf(v.w) > thr) ? (v.w > 0.f ? 1 : -1) : 0;
        out[q] = (b0 & 0xff) | ((b1 & 0xff) << 8) |
                 ((b2 & 0xff) << 16) | ((b3 & 0xff) << 24);
    }
    i32x4 o = {out[0], out[1], out[2], out[3]};
    ((i32x4*)wq)[g] = o;
}

__global__ __launch_bounds__(256) void rmsnorm_xq(const float* __restrict__ x,
                                                  char* __restrict__ xq) {
    const int row = blockIdx.x;
    const float4* xr = (const float4*)(x + (size_t)row * D_MODEL);
    float4 v = xr[threadIdx.x];
    float ss = v.x * v.x + v.y * v.y + v.z * v.z + v.w * v.w;
    #pragma unroll
    for (int off = 32; off > 0; off >>= 1) ss += __shfl_down(ss, off);
    __shared__ float sm[4];
    int lane = threadIdx.x & 63, wid = threadIdx.x >> 6;
    if (lane == 0) sm[wid] = ss;
    __syncthreads();
    float tot = sm[0] + sm[1] + sm[2] + sm[3];
    float s = 24.0f / (sqrtf(tot) * (1.0f / 32.0f) + 1e-8f);
    int b0 = q8(v.x * s), b1 = q8(v.y * s), b2 = q8(v.z * s), b3 = q8(v.w * s);
    ((int*)(xq + (size_t)row * D_MODEL))[threadIdx.x] =
        (b0 & 0xff) | ((b1 & 0xff) << 8) | ((b2 & 0xff) << 16) | ((b3 & 0xff) << 24);
}

__global__ __launch_bounds__(256) void rowscale_hq(const char* __restrict__ hq,
                                                   float* __restrict__ rs) {
    const int row = blockIdx.x;
    const int4* hr = (const int4*)(hq + (size_t)row * D_FF);
    int4 d = hr[threadIdx.x];
    float ss = 0.f;
    #pragma unroll
    for (int w = 0; w < 4; ++w) {
        int dw = (w == 0) ? d.x : (w == 1) ? d.y : (w == 2) ? d.z : d.w;
        #pragma unroll
        for (int b = 0; b < 4; ++b) {
            int q = (int)(char)((dw >> (8 * b)) & 0xff);
            ss += (float)(q * q);
        }
    }
    #pragma unroll
    for (int off = 32; off > 0; off >>= 1) ss += __shfl_down(ss, off);
    __shared__ float sm[4];
    int lane = threadIdx.x & 63, wid = threadIdx.x >> 6;
    if (lane == 0) sm[wid] = ss;
    __syncthreads();
    if (threadIdx.x == 0) {
        float tot = sm[0] + sm[1] + sm[2] + sm[3];
        rs[row] = 1.0f / (sqrtf(tot) * (1.0f / 64.0f) + 1e-8f);
    }
}

// ---------------------------------------------------------------------------
// i8 GEMM: C[m][n] = sum_k A[m,k]*B[n,k]; A i8 K-contig (LDS-staged),
// B pre-packed fragment-order (global->VGPR direct).
// LDS: 3 x 16KB A buffers (256 rows x 64B, swizzle ch ^= (row>>1)&3).
// Per tile: P1 {4 A ds_read, LOADB B(t+1) x4, 16 MFMA};
//           P2 {4 A ds_read, gload_lds A(t+2) x2, 16 MFMA}; vmcnt(2); BAR.
// vmcnt(2): only A(t+2)'s 2 loads may remain in flight -> A(t+1) and B(t+1)
// landed at the barrier, regardless of instruction motion.
// ---------------------------------------------------------------------------
template <int EPI, int KDIM, int NBLKN>
__global__ __launch_bounds__(512, 1) void gemm_i8r(const char* __restrict__ A,
                                                   const char* __restrict__ Bq,
                                                   char* __restrict__ Cq,
                                                   float* __restrict__ Cf,
                                                   const float* __restrict__ rowscale,
                                                   int nwg) {
    constexpr int BUFB = 16384;
    constexpr int NT = KDIM / 64;
    constexpr int KS = KDIM / 64;
    __shared__ char smem[3 * BUFB];

    const int tid = threadIdx.x;
    const int bid = blockIdx.x;
    const int swz = (bid & 7) * (nwg >> 3) + (bid >> 3);
    const uint m0 = (uint)(swz / NBLKN) * 256u;
    const uint n0 = (uint)(swz % NBLKN) * 256u;

    const int lane = tid & 63;
    const int wid  = tid >> 6;
    const int wm   = wid >> 2;                  // 0..1 -> 128-row slice
    const int wn   = wid & 3;                   // 0..3 -> 64-col slice
    const int lr   = lane & 15;
    const int lk   = lane >> 4;                 // 16B k-chunk 0..3

    // A staging source (inverse swizzle), per inst in {0,1}
    uint aOff[2];
    #pragma unroll
    for (int inst = 0; inst < 2; ++inst) {
        uint s = (uint)tid + (uint)inst * 512u;
        uint row = s >> 2, ch = s & 3u;
        uint src = ((ch ^ ((row >> 1) & 3u)) << 4);
        aOff[inst] = (m0 + row) * (uint)KDIM + src;
    }
    const uint dstOff = (uint)tid * 16u;

    // A fragment read offsets (bytes)
    uint offA[8];
    #pragma unroll
    for (int i = 0; i < 8; ++i) {
        uint row = (uint)(wm * 128 + i * 16 + lr);
        offA[i] = row * 64u + (((uint)lk ^ ((row >> 1) & 3u)) << 4);
    }

    // B fragment base pointers: frag (nfBase+i, ks) at ((nf*KS+ks)*64+lane)*16
    const int nfBase = (int)(n0 >> 4) + wn * 4;
    const char* bPtr[4];
    #pragma unroll
    for (int i = 0; i < 4; ++i)
        bPtr[i] = Bq + ((size_t)(nfBase + i) * KS * 64 + (size_t)lane) * 16;

    i32x4 acc[8][4];
    #pragma unroll
    for (int mi = 0; mi < 8; ++mi)
        #pragma unroll
        for (int ni = 0; ni < 4; ++ni)
            acc[mi][ni] = (i32x4){0, 0, 0, 0};

    i32x4 bS0[4], bS1[4];       // B reg sets: even tiles use bS0, odd bS1

    // ---- prologue: stage A(0)->buf0, A(1)->buf1; load B(0)->bS0 ----
    {
        gload_lds16(A + aOff[0],       smem +            0 + dstOff);
        gload_lds16(A + aOff[1],       smem +         8192 + dstOff);
        gload_lds16(A + aOff[0] + 64u, smem + BUFB +     0 + dstOff);
        gload_lds16(A + aOff[1] + 64u, smem + BUFB +  8192 + dstOff);
        #pragma unroll
        for (int i = 0; i < 4; ++i) LOADB(bS0[i], bPtr[i]);
    }
    VMCNT(0);
    BAR();

    int cur = 0;
    #pragma unroll 1
    for (int t = 0; t < NT; t += 2) {
        int c1 = cur + 1; if (c1 > 2) c1 -= 3;
        int c2 = c1 + 1;  if (c2 > 2) c2 -= 3;

#define TILE(T, CBUF, SBUF, BUSE, BLOAD)                                        \
        {                                                                       \
            const char* cb = smem + (CBUF) * BUFB;                              \
            char* sb = smem + (SBUF) * BUFB;                                    \
            const uint kc = (uint)((T) + 2) * 64u;                              \
            const bool doS = ((T) + 2 < NT);                                    \
            const bool doB = ((T) + 1 < NT);                                    \
            const size_t bko = (size_t)((T) + 1) * 1024;                        \
            i32x4 av[4];                                                        \
            /* P1: A-h0 reads; issue B(T+1); 16 MFMA */                         \
            _Pragma("unroll")                                                   \
            for (int i = 0; i < 4; ++i) av[i] = *(const i32x4*)(cb + offA[i]);  \
            if (doB) {                                                          \
                _Pragma("unroll")                                               \
                for (int i = 0; i < 4; ++i) LOADB(BLOAD[i], bPtr[i] + bko);     \
            }                                                                   \
            __builtin_amdgcn_s_setprio(1);                                      \
            _Pragma("unroll")                                                   \
            for (int mi = 0; mi < 4; ++mi)                                      \
                _Pragma("unroll")                                               \
                for (int ni = 0; ni < 4; ++ni)                                  \
                    acc[mi][ni] = __builtin_amdgcn_mfma_i32_16x16x64_i8(        \
                        av[mi], BUSE[ni], acc[mi][ni], 0, 0, 0);                \
            __builtin_amdgcn_s_setprio(0);                                      \
            /* P2: A-h1 reads; stage A(T+2); 16 MFMA */                         \
            _Pragma("unroll")                                                   \
            for (int i = 0; i < 4; ++i) av[i] = *(const i32x4*)(cb + offA[4+i]);\
            if (doS) {                                                          \
                gload_lds16(A + aOff[0] + kc, sb +    0 + dstOff);              \
                gload_lds16(A + aOff[1] + kc, sb + 8192 + dstOff);              \
            }                                                                   \
            __builtin_amdgcn_s_setprio(1);                                      \
            _Pragma("unroll")                                                   \
            for (int mi = 0; mi < 4; ++mi)                                      \
                _Pragma("unroll")                                               \
                for (int ni = 0; ni < 4; ++ni)                                  \
                    acc[4 + mi][ni] = __builtin_amdgcn_mfma_i32_16x16x64_i8(    \
                        av[mi], BUSE[ni], acc[4 + mi][ni], 0, 0, 0);            \
            __builtin_amdgcn_s_setprio(0);                                      \
            if (doS) { VMCNT(2); } else { VMCNT(0); }                           \
            BAR();                                                              \
        }

        TILE(t,     cur, c2,  bS0, bS1)
        TILE(t + 1, c1,  cur, bS1, bS0)
#undef TILE
        cur = c2;
    }

    // epilogue: C/D frag mapping col = lane&15, row = (lane>>4)*4 + reg
    constexpr uint N = (uint)NBLKN * 256u;
    #pragma unroll
    for (int mi = 0; mi < 8; ++mi) {
        #pragma unroll
        for (int j = 0; j < 4; ++j) {
            const uint gr = m0 + (uint)(wm * 128 + mi * 16 + lk * 4 + j);
            float s = 0.f;
            if (EPI == 1) s = rowscale[gr];
            #pragma unroll
            for (int ni = 0; ni < 4; ++ni) {
                const uint gc = n0 + (uint)(wn * 64 + ni * 16 + lr);
                if (EPI == 0) {
                    float g = gelu_fast((float)acc[mi][ni][j] * (1.0f / 24.0f));
                    Cq[gr * N + gc] = (char)q8(g);
                } else {
                    Cf[gr * N + gc] = (float)acc[mi][ni][j] * s;
                }
            }
        }
    }
}

// ---------------------------------------------------------------------------
extern "C" void kernel_launch(void* const* d_in, const int* in_sizes, int n_in,
                              void* d_out, int out_size, void* d_ws, size_t ws_size,
                              hipStream_t stream) {
    const float* x    = (const float*)d_in[0];
    const float* w_up = (const float*)d_in[1];
    const float* w_dn = (const float*)d_in[2];
    float* out = (float*)d_out;

    uint8_t* ws = (uint8_t*)d_ws;
    char* hq  = (char*)(ws);                                   // 64 MB
    char* xq  = (char*)(ws + 67108864);                        // 16 MB
    char* wqu = (char*)(ws + 67108864 + 16777216);             // 4 MB (packed)
    char* wqd = (char*)(ws + 67108864 + 16777216 + 4194304);   // 4 MB (packed)
    float*  rs   = (float*)(ws + 67108864 + 16777216 + 2 * 4194304);
    double* alph = (double*)(ws + 67108864 + 16777216 + 2 * 4194304 + 65536);

    hipMemsetAsync(alph, 0, 16, stream);

    absmean_reduce<<<256, 256, 0, stream>>>(w_up, alph + 0);
    absmean_reduce<<<256, 256, 0, stream>>>(w_dn, alph + 1);
    quant_pack_i8<D_MODEL><<<NW / 4096, 256, 0, stream>>>(w_up, alph + 0, wqu);
    quant_pack_i8<D_FF><<<NW / 4096, 256, 0, stream>>>(w_dn, alph + 1, wqd);
    rmsnorm_xq<<<M_ROWS, 256, 0, stream>>>(x, xq);

    // L1: hq = q8(gelu((xq @ wqu^T)/24))  [16384 x 4096], K=1024
    gemm_i8r<0, D_MODEL, 16><<<1024, 512, 0, stream>>>(
        xq, wqu, hq, nullptr, nullptr, 1024);

    rowscale_hq<<<M_ROWS, 256, 0, stream>>>(hq, rs);

    // L2: out = (hq @ wqd^T) * rs[m]  [16384 x 1024], K=4096
    gemm_i8r<1, D_FF, 4><<<256, 512, 0, stream>>>(
        hq, wqd, nullptr, out, rs, 256);
}